// Round 8
// baseline (383.748 us; speedup 1.0000x reference)
//
#include <hip/hip_runtime.h>

typedef unsigned short u16;
typedef unsigned int u32;
typedef __attribute__((ext_vector_type(8))) short short8;   // 8 x bf16
typedef __attribute__((ext_vector_type(4))) float f32x4;

// ---------------- workspace layout (bytes) ----------------
#define OFF_WM    0         // float[801]: wmean[0..799] (pad 0), [800]=mean(b_in)
#define OFF_WINF  3584      // u16 [25][8][64][8]  W_in B-fragment-linear   (204800 B)
#define OFF_WEGF  208384    // u16 [6][17][64][8]  experts+gate frag-linear (104448 B)
#define OFF_WCTXF 312832    // u16 [2][8][64][8]   W_ctx frag-linear        (16384 B)
#define OFF_WOUTF 329216    // u16 [4][64][8]      W_out frag-linear        (4096 B)
#define OFF_T     524288    // float[B]            t = x.wm per row
#define OFF_XF    1048576   // u16 [B/16][25][64][8]  x A-fragment-linear (~105 MB)

__device__ __forceinline__ u16 f2bf(float x) {
  union { float f; u32 u; } v; v.f = x;
  u32 r = v.u + 0x7FFFu + ((v.u >> 16) & 1u);   // RNE
  return (u16)(r >> 16);
}

// ------------------------------------------------------------------
// Prep: wmean for the exact fp32 t path; all weights -> bf16 in
// MFMA-B-fragment-linear order: frag[tile][lane][j] with
// k = kt*32 + (lane>>4)*8 + j, n = ct*16 + (lane&15).
// ------------------------------------------------------------------
__global__ void prep_kernel(const float* __restrict__ W_in, const float* __restrict__ b_in,
                            const float* __restrict__ W_gate, const float* __restrict__ W_exp,
                            const float* __restrict__ W_ctx, const float* __restrict__ W_out,
                            float* __restrict__ wm, u16* __restrict__ WinF,
                            u16* __restrict__ WegF, u16* __restrict__ WctxF,
                            u16* __restrict__ WoutF) {
  int idx = blockIdx.x * 256 + threadIdx.x;
  if (idx < 801) {
    if (idx == 800) {
      float s = 0.f;
      for (int j = 0; j < 128; ++j) s += b_in[j];
      wm[800] = s * (1.f / 128.f);
    } else if (idx >= 784) {
      wm[idx] = 0.f;
    } else {
      float s = 0.f;
      for (int j = 0; j < 128; ++j) s += W_in[idx * 128 + j];
      wm[idx] = s * (1.f / 128.f);
    }
  } else if (idx < 103201) {                    // WinF: 25*8 tiles
    int f = idx - 801;
    int j = f & 7, lane = (f >> 3) & 63, tile = f >> 9;
    int ct = tile & 7, kt = tile >> 3;
    int k = kt * 32 + ((lane >> 4) << 3) + j;
    int n = ct * 16 + (lane & 15);
    WinF[f] = (k < 784) ? f2bf(W_in[k * 128 + n]) : (u16)0;
  } else if (idx < 155425) {                    // WegF: 6*17 tiles
    int f = idx - 103201;
    int j = f & 7, lane = (f >> 3) & 63, tile = f >> 9;
    int kt = tile / 17, ct = tile - kt * 17;
    int k = kt * 32 + ((lane >> 4) << 3) + j;
    int n = ct * 16 + (lane & 15);
    float v = 0.f;
    if (n < 256) { int e = n >> 6, h = n & 63; v = W_exp[(e * 192 + k) * 64 + h]; }
    else if (n < 260) v = W_gate[k * 4 + (n - 256)];
    WegF[f] = f2bf(v);
  } else if (idx < 163617) {                    // WctxF: 2*8 tiles
    int f = idx - 155425;
    int j = f & 7, lane = (f >> 3) & 63, tile = f >> 9;
    int ct = tile & 7, kt = tile >> 3;
    int k = kt * 32 + ((lane >> 4) << 3) + j;
    int n = ct * 16 + (lane & 15);
    WctxF[f] = f2bf(W_ctx[k * 128 + n]);
  } else if (idx < 165665) {                    // WoutF: 4 tiles (N padded 3->16)
    int f = idx - 163617;
    int j = f & 7, lane = (f >> 3) & 63, kt = f >> 9;
    int k = kt * 32 + ((lane >> 4) << 3) + j;
    int n = lane & 15;
    WoutF[f] = (n < 3) ? f2bf(W_out[k * 3 + n]) : (u16)0;
  }
}

// ------------------------------------------------------------------
// prepx: one streaming pass over x. Each wave owns one 16-row tile
// and loops kt=0..24:
//  (a) pack x -> bf16 A-fragment-linear xf[rt][kt][lane][8]
//      (row = rt*16 + (lane&15), k = kt*32 + (lane>>4)*8 + j),
//      identical f2bf rounding -> bit-identical MFMA inputs.
//  (b) accumulate exact fp32 t[row] = x.wm per lane in the SAME order
//      as the round-6 in-fused path (per-kt dot8, then qr shuffle
//      reduce) -> bit-identical t. Direct store, no atomics.
// Rationale (rounds 3/6 counters): fused time is invariant to x's
// residency -> x cost is per-request latency on the 3136B-strided
// reads inside fused's barrier-fenced chain. Here the same reads sit
// in a dependency-free streaming kernel (16 waves/CU, no barriers):
// TLP hides them. xf writes are 16B/lane fully coalesced.
// ------------------------------------------------------------------
__global__ __launch_bounds__(256, 8)
void prepx_kernel(const float* __restrict__ x, const float* __restrict__ wm,
                  u16* __restrict__ xf, float* __restrict__ t, int nrt) {
  const int rt = blockIdx.x * 4 + (threadIdx.x >> 6);
  if (rt >= nrt) return;
  const int ln = threadIdx.x & 63;
  const int cb = ln & 15;
  const int qr = ln >> 4;
  const int row = rt * 16 + cb;
  const float* xr = x + (size_t)row * 784;
  u16* dst = xf + ((size_t)rt * 25 * 64 + ln) * 8;

  float part = 0.f;
  for (int kt = 0; kt < 25; ++kt) {
    const int k0 = kt * 32 + qr * 8;
    union { short8 s; u32 u[4]; } af;
    if (k0 < 784) {
      float4 a0 = *(const float4*)(xr + k0);
      float4 a1 = *(const float4*)(xr + k0 + 4);
      const float4 m0 = *(const float4*)(wm + k0);
      const float4 m1 = *(const float4*)(wm + k0 + 4);
      part += a0.x * m0.x + a0.y * m0.y + a0.z * m0.z + a0.w * m0.w
            + a1.x * m1.x + a1.y * m1.y + a1.z * m1.z + a1.w * m1.w;
      af.u[0] = (u32)f2bf(a0.x) | ((u32)f2bf(a0.y) << 16);
      af.u[1] = (u32)f2bf(a0.z) | ((u32)f2bf(a0.w) << 16);
      af.u[2] = (u32)f2bf(a1.x) | ((u32)f2bf(a1.y) << 16);
      af.u[3] = (u32)f2bf(a1.z) | ((u32)f2bf(a1.w) << 16);
    } else {
      af.u[0] = 0; af.u[1] = 0; af.u[2] = 0; af.u[3] = 0;
    }
    *(short8*)(dst + kt * 512) = af.s;
  }
  part += __shfl_xor(part, 16);
  part += __shfl_xor(part, 32);
  if (ln < 16) t[row] = part;
}

// ------------------------------------------------------------------
// Fused forward (xf path): 4 waves/WG, each wave owns 32 rows (two
// 16-row MFMA groups). Weight fragments block-staged in LDS (round
// 6); x consumed as pre-packed bf16 A-fragments -- phase 1 per kt is
// 2 coalesced A-loads + 2 staging loads + 16 MFMA. No fp32 x, no wm,
// no f2bf, no divergence, no shuffle reduces in the hot loop.
// LDS (77824 B/block -> 2 blocks/CU): per-wave enh 2 x 3840 u16
// (enh [6][16][40]; cmb aliases [0,1280); ctx aliases [1280,3456));
// stage 8192 u16 shared.
// ------------------------------------------------------------------
__global__ __launch_bounds__(256, 2)
void fused_kernel_xf(const u16* __restrict__ xf, const float* __restrict__ t,
                     const float* __restrict__ b_in, const float* __restrict__ b_gate,
                     const float* __restrict__ b_exp, const float* __restrict__ b_ctx,
                     const float* __restrict__ b_out,
                     const float* __restrict__ wm, const u16* __restrict__ WinF,
                     const u16* __restrict__ WegF, const u16* __restrict__ WctxF,
                     const u16* __restrict__ WoutF,
                     float* __restrict__ out) {
  __shared__ __align__(16) u16 smem[4 * 7680 + 8192];
  const int tid = threadIdx.x;
  const int wv = tid >> 6;
  const int ln = tid & 63;
  const int cb = ln & 15;
  const int qr = ln >> 4;
  u16* enh0 = smem + wv * 7680;
  u16* enh1 = enh0 + 3840;
  u16* cmb0 = enh0;
  u16* cmb1 = enh1;
  u16* ctx0 = enh0 + 1280;
  u16* ctx1 = enh1 + 1280;
  u16* stg  = smem + 4 * 7680;

  const int grow = blockIdx.x * 128 + wv * 32;
  const int rtA = grow >> 4;
  const u16* xfA = xf + ((size_t)rtA * 25 * 64 + ln) * 8;
  const u16* xfB = xfA + (size_t)25 * 512;

  const f32x4 vz = {0.f, 0.f, 0.f, 0.f};

  // ---- Phase 1 ----
  f32x4 acc0[8], acc1[8];
  #pragma unroll
  for (int i = 0; i < 8; ++i) { acc0[i] = vz; acc1[i] = vz; }

  {
    const u16* src = WinF + tid * 8;
    short8 r0 = *(const short8*)(src);
    short8 r1 = *(const short8*)(src + 2048);
    *(short8*)(stg + tid * 8) = r0;
    *(short8*)(stg + 2048 + tid * 8) = r1;
  }
  __syncthreads();

  for (int kt = 0; kt < 25; ++kt) {
    const int buf = (kt & 1) << 12;
    short8 r0 = short8{0,0,0,0,0,0,0,0}, r1 = r0;
    const bool pf = (kt < 24);
    if (pf) {
      const u16* src = WinF + (size_t)(kt + 1) * 4096 + tid * 8;
      r0 = *(const short8*)(src);
      r1 = *(const short8*)(src + 2048);
    }

    short8 A0 = *(const short8*)(xfA + kt * 512);
    short8 A1 = *(const short8*)(xfB + kt * 512);

    short8 Bf[8];
    #pragma unroll
    for (int ct = 0; ct < 8; ++ct)
      Bf[ct] = *(const short8*)(stg + buf + ct * 512 + ln * 8);

    #pragma unroll
    for (int ct = 0; ct < 8; ++ct) {
      acc0[ct] = __builtin_amdgcn_mfma_f32_16x16x32_bf16(A0, Bf[ct], acc0[ct], 0, 0, 0);
      acc1[ct] = __builtin_amdgcn_mfma_f32_16x16x32_bf16(A1, Bf[ct], acc1[ct], 0, 0, 0);
    }

    if (pf) {
      u16* dst = stg + (buf ^ 4096);
      *(short8*)(dst + tid * 8) = r0;
      *(short8*)(dst + 2048 + tid * 8) = r1;
    }
    __syncthreads();
  }

  const float mb = wm[800];
  const float t0 = t[grow + cb] + mb;
  const float t1 = t[grow + 16 + cb] + mb;

  #pragma unroll
  for (int ct = 0; ct < 8; ++ct) {
    float bi = b_in[ct * 16 + cb];
    u16* d0 = enh0 + (ct >> 1) * 640 + (ct & 1) * 16 + cb;
    u16* d1 = enh1 + (ct >> 1) * 640 + (ct & 1) * 16 + cb;
    #pragma unroll
    for (int i = 0; i < 4; ++i) {
      d0[(qr * 4 + i) * 40] = f2bf(acc0[ct][i] + bi);
      d1[(qr * 4 + i) * 40] = f2bf(acc1[ct][i] + bi);
    }
  }
  #pragma unroll
  for (int g = 0; g < 2; ++g) {
    float t_ = g ? t1 : t0;
    u16* eW = g ? enh1 : enh0;
    float phi = 7.f * t_;
    float ss, cc, sd, cd;
    sincosf(phi * (float)(qr * 8 + 1), &ss, &cc);
    sincosf(phi, &sd, &cd);
    u16* pc = eW + 4 * 640 + cb * 40 + qr * 8;
    u16* ps = eW + 5 * 640 + cb * 40 + qr * 8;
    #pragma unroll
    for (int m = 0; m < 8; ++m) {
      pc[m] = f2bf(cc);
      ps[m] = f2bf(ss);
      float nc = cc * cd - ss * sd;
      ss = ss * cd + cc * sd;
      cc = nc;
    }
  }

  // ---- Phase 2 ----
  const u16* gbase = WegF + ln * 8;
  f32x4 g0 = vz, g1 = vz;
  #pragma unroll
  for (int kt = 0; kt < 6; ++kt) {
    short8 A0 = *(const short8*)(enh0 + kt * 640 + cb * 40 + qr * 8);
    short8 A1 = *(const short8*)(enh1 + kt * 640 + cb * 40 + qr * 8);
    short8 Bg = *(const short8*)(gbase + (size_t)(kt * 17 + 16) * 512);
    g0 = __builtin_amdgcn_mfma_f32_16x16x32_bf16(A0, Bg, g0, 0, 0, 0);
    g1 = __builtin_amdgcn_mfma_f32_16x16x32_bf16(A1, Bg, g1, 0, 0, 0);
  }

  float ge0[4][4], ge1[4][4];
  {
    float bg = b_gate[cb & 3];
    #pragma unroll
    for (int i = 0; i < 4; ++i) {
      {
        float gi = g0[i] + bg;
        float mx = fmaxf(gi, __shfl_xor(gi, 1));
        mx = fmaxf(mx, __shfl_xor(mx, 2));
        float ev = __expf(gi - mx);
        float sv = ev + __shfl_xor(ev, 1);
        sv += __shfl_xor(sv, 2);
        float g = ev / sv;
        int base = qr * 16;
        ge0[0][i] = __shfl(g, base + 0);
        ge0[1][i] = __shfl(g, base + 1);
        ge0[2][i] = __shfl(g, base + 2);
        ge0[3][i] = __shfl(g, base + 3);
      }
      {
        float gi = g1[i] + bg;
        float mx = fmaxf(gi, __shfl_xor(gi, 1));
        mx = fmaxf(mx, __shfl_xor(mx, 2));
        float ev = __expf(gi - mx);
        float sv = ev + __shfl_xor(ev, 1);
        sv += __shfl_xor(sv, 2);
        float g = ev / sv;
        int base = qr * 16;
        ge1[0][i] = __shfl(g, base + 0);
        ge1[1][i] = __shfl(g, base + 1);
        ge1[2][i] = __shfl(g, base + 2);
        ge1[3][i] = __shfl(g, base + 3);
      }
    }
  }

  f32x4 ae0[16], ae1[16];
  #pragma unroll
  for (int c = 0; c < 16; ++c) { ae0[c] = vz; ae1[c] = vz; }
  for (int kt = 0; kt < 6; ++kt) {
    __syncthreads();
    {
      const u16* src = WegF + (size_t)kt * 17 * 512 + tid * 8;
      short8 s0 = *(const short8*)(src);
      short8 s1 = *(const short8*)(src + 2048);
      short8 s2 = *(const short8*)(src + 4096);
      short8 s3 = *(const short8*)(src + 6144);
      *(short8*)(stg + tid * 8) = s0;
      *(short8*)(stg + 2048 + tid * 8) = s1;
      *(short8*)(stg + 4096 + tid * 8) = s2;
      *(short8*)(stg + 6144 + tid * 8) = s3;
    }
    __syncthreads();
    short8 A0 = *(const short8*)(enh0 + kt * 640 + cb * 40 + qr * 8);
    short8 A1 = *(const short8*)(enh1 + kt * 640 + cb * 40 + qr * 8);
    #pragma unroll
    for (int c = 0; c < 16; ++c) {
      short8 Bf = *(const short8*)(stg + c * 512 + ln * 8);
      ae0[c] = __builtin_amdgcn_mfma_f32_16x16x32_bf16(A0, Bf, ae0[c], 0, 0, 0);
      ae1[c] = __builtin_amdgcn_mfma_f32_16x16x32_bf16(A1, Bf, ae1[c], 0, 0, 0);
    }
  }

  f32x4 cA[4], cB[4];
  #pragma unroll
  for (int i = 0; i < 4; ++i) { cA[i] = vz; cB[i] = vz; }
  #pragma unroll
  for (int e = 0; e < 4; ++e) {
    #pragma unroll
    for (int c2 = 0; c2 < 4; ++c2) {
      float be = b_exp[e * 64 + c2 * 16 + cb];
      #pragma unroll
      for (int i = 0; i < 4; ++i) {
        cA[c2][i] += ge0[e][i] * fmaxf(ae0[e * 4 + c2][i] + be, 0.f);
        cB[c2][i] += ge1[e][i] * fmaxf(ae1[e * 4 + c2][i] + be, 0.f);
      }
    }
  }
  #pragma unroll
  for (int c2 = 0; c2 < 4; ++c2) {
    u16* d0 = cmb0 + (c2 >> 1) * 640 + (c2 & 1) * 16 + cb;
    u16* d1 = cmb1 + (c2 >> 1) * 640 + (c2 & 1) * 16 + cb;
    #pragma unroll
    for (int i = 0; i < 4; ++i) {
      d0[(qr * 4 + i) * 40] = f2bf(cA[c2][i]);
      d1[(qr * 4 + i) * 40] = f2bf(cB[c2][i]);
    }
  }

  // ---- Phase 3 ----
  __syncthreads();
  {
    const u16* src = WctxF + tid * 8;
    short8 s0 = *(const short8*)(src);
    short8 s1 = *(const short8*)(src + 2048);
    short8 s2 = *(const short8*)(src + 4096);
    short8 s3 = *(const short8*)(src + 6144);
    *(short8*)(stg + tid * 8) = s0;
    *(short8*)(stg + 2048 + tid * 8) = s1;
    *(short8*)(stg + 4096 + tid * 8) = s2;
    *(short8*)(stg + 6144 + tid * 8) = s3;
  }
  __syncthreads();
  f32x4 c30[8], c31[8];
  #pragma unroll
  for (int i = 0; i < 8; ++i) { c30[i] = vz; c31[i] = vz; }
  #pragma unroll
  for (int kt = 0; kt < 2; ++kt) {
    short8 A0 = *(const short8*)(cmb0 + kt * 640 + cb * 40 + qr * 8);
    short8 A1 = *(const short8*)(cmb1 + kt * 640 + cb * 40 + qr * 8);
    #pragma unroll
    for (int ct = 0; ct < 8; ++ct) {
      short8 Bf = *(const short8*)(stg + (kt * 8 + ct) * 512 + ln * 8);
      c30[ct] = __builtin_amdgcn_mfma_f32_16x16x32_bf16(A0, Bf, c30[ct], 0, 0, 0);
      c31[ct] = __builtin_amdgcn_mfma_f32_16x16x32_bf16(A1, Bf, c31[ct], 0, 0, 0);
    }
  }
  #pragma unroll
  for (int ct = 0; ct < 8; ++ct) {
    float bc = b_ctx[ct * 16 + cb];
    u16* d0 = ctx0 + ct * 16 + cb;
    u16* d1 = ctx1 + ct * 16 + cb;
    #pragma unroll
    for (int i = 0; i < 4; ++i) {
      float v0 = c30[ct][i] + bc;
      float e0 = __expf(2.f * v0);
      d0[(qr * 4 + i) * 136] = f2bf(1.f - 2.f / (e0 + 1.f));
      float v1 = c31[ct][i] + bc;
      float e1 = __expf(2.f * v1);
      d1[(qr * 4 + i) * 136] = f2bf(1.f - 2.f / (e1 + 1.f));
    }
  }

  // ---- Phase 4 ----
  __syncthreads();
  {
    short8 s0 = *(const short8*)(WoutF + tid * 8);
    *(short8*)(stg + tid * 8) = s0;
  }
  __syncthreads();
  f32x4 a40 = vz, a41 = vz;
  #pragma unroll
  for (int kt = 0; kt < 4; ++kt) {
    short8 A0 = *(const short8*)(ctx0 + cb * 136 + kt * 32 + qr * 8);
    short8 A1 = *(const short8*)(ctx1 + cb * 136 + kt * 32 + qr * 8);
    short8 Bf = *(const short8*)(stg + kt * 512 + ln * 8);
    a40 = __builtin_amdgcn_mfma_f32_16x16x32_bf16(A0, Bf, a40, 0, 0, 0);
    a41 = __builtin_amdgcn_mfma_f32_16x16x32_bf16(A1, Bf, a41, 0, 0, 0);
  }
  if (cb < 3) {
    float bo = b_out[cb];
    #pragma unroll
    for (int i = 0; i < 4; ++i) {
      out[(size_t)(grow + qr * 4 + i) * 3 + cb] = a40[i] + bo;
      out[(size_t)(grow + 16 + qr * 4 + i) * 3 + cb] = a41[i] + bo;
    }
  }
}

// ------------------------------------------------------------------
// Fallback fused kernel (round-6 verified, 329 us total): x read
// directly; in-kernel fp32 t. Used when ws_size can't hold xf.
// ------------------------------------------------------------------
__global__ __launch_bounds__(256, 2)
void fused_kernel_x(const float* __restrict__ x,
                    const float* __restrict__ b_in, const float* __restrict__ b_gate,
                    const float* __restrict__ b_exp, const float* __restrict__ b_ctx,
                    const float* __restrict__ b_out,
                    const float* __restrict__ wm, const u16* __restrict__ WinF,
                    const u16* __restrict__ WegF, const u16* __restrict__ WctxF,
                    const u16* __restrict__ WoutF,
                    float* __restrict__ out) {
  __shared__ __align__(16) u16 smem[4 * 7680 + 8192];
  const int tid = threadIdx.x;
  const int wv = tid >> 6;
  const int ln = tid & 63;
  const int cb = ln & 15;
  const int qr = ln >> 4;
  u16* enh0 = smem + wv * 7680;
  u16* enh1 = enh0 + 3840;
  u16* cmb0 = enh0;
  u16* cmb1 = enh1;
  u16* ctx0 = enh0 + 1280;
  u16* ctx1 = enh1 + 1280;
  u16* stg  = smem + 4 * 7680;

  const int grow = blockIdx.x * 128 + wv * 32;
  const float* xr0 = x + (size_t)(grow + cb) * 784;
  const float* xr1 = xr0 + (size_t)16 * 784;

  const f32x4 vz = {0.f, 0.f, 0.f, 0.f};

  f32x4 acc0[8], acc1[8];
  #pragma unroll
  for (int i = 0; i < 8; ++i) { acc0[i] = vz; acc1[i] = vz; }
  float tp0 = 0.f, tp1 = 0.f;

  {
    const u16* src = WinF + tid * 8;
    short8 r0 = *(const short8*)(src);
    short8 r1 = *(const short8*)(src + 2048);
    *(short8*)(stg + tid * 8) = r0;
    *(short8*)(stg + 2048 + tid * 8) = r1;
  }
  __syncthreads();

  for (int kt = 0; kt < 25; ++kt) {
    const int buf = (kt & 1) << 12;
    short8 r0 = short8{0,0,0,0,0,0,0,0}, r1 = r0;
    const bool pf = (kt < 24);
    if (pf) {
      const u16* src = WinF + (size_t)(kt + 1) * 4096 + tid * 8;
      r0 = *(const short8*)(src);
      r1 = *(const short8*)(src + 2048);
    }

    const int k0 = kt * 32 + qr * 8;
    union { short8 s; u32 u[4]; } af, bf;
    {
      float4 a0 = make_float4(0.f, 0.f, 0.f, 0.f), a1 = a0;
      float4 b0 = a0, b1 = a0, m0 = a0, m1 = a0;
      if (k0 < 784) {
        a0 = *(const float4*)(xr0 + k0);
        a1 = *(const float4*)(xr0 + k0 + 4);
        b0 = *(const float4*)(xr1 + k0);
        b1 = *(const float4*)(xr1 + k0 + 4);
        m0 = *(const float4*)(wm + k0);
        m1 = *(const float4*)(wm + k0 + 4);
        tp0 += a0.x * m0.x + a0.y * m0.y + a0.z * m0.z + a0.w * m0.w
             + a1.x * m1.x + a1.y * m1.y + a1.z * m1.z + a1.w * m1.w;
        tp1 += b0.x * m0.x + b0.y * m0.y + b0.z * m0.z + b0.w * m0.w
             + b1.x * m1.x + b1.y * m1.y + b1.z * m1.z + b1.w * m1.w;
      }
      af.u[0] = (u32)f2bf(a0.x) | ((u32)f2bf(a0.y) << 16);
      af.u[1] = (u32)f2bf(a0.z) | ((u32)f2bf(a0.w) << 16);
      af.u[2] = (u32)f2bf(a1.x) | ((u32)f2bf(a1.y) << 16);
      af.u[3] = (u32)f2bf(a1.z) | ((u32)f2bf(a1.w) << 16);
      bf.u[0] = (u32)f2bf(b0.x) | ((u32)f2bf(b0.y) << 16);
      bf.u[1] = (u32)f2bf(b0.z) | ((u32)f2bf(b0.w) << 16);
      bf.u[2] = (u32)f2bf(b1.x) | ((u32)f2bf(b1.y) << 16);
      bf.u[3] = (u32)f2bf(b1.z) | ((u32)f2bf(b1.w) << 16);
    }

    short8 Bf[8];
    #pragma unroll
    for (int ct = 0; ct < 8; ++ct)
      Bf[ct] = *(const short8*)(stg + buf + ct * 512 + ln * 8);

    #pragma unroll
    for (int ct = 0; ct < 8; ++ct) {
      acc0[ct] = __builtin_amdgcn_mfma_f32_16x16x32_bf16(af.s, Bf[ct], acc0[ct], 0, 0, 0);
      acc1[ct] = __builtin_amdgcn_mfma_f32_16x16x32_bf16(bf.s, Bf[ct], acc1[ct], 0, 0, 0);
    }

    if (pf) {
      u16* dst = stg + (buf ^ 4096);
      *(short8*)(dst + tid * 8) = r0;
      *(short8*)(dst + 2048 + tid * 8) = r1;
    }
    __syncthreads();
  }

  tp0 += __shfl_xor(tp0, 16);
  tp0 += __shfl_xor(tp0, 32);
  tp1 += __shfl_xor(tp1, 16);
  tp1 += __shfl_xor(tp1, 32);
  const float mb = wm[800];
  const float t0 = tp0 + mb;
  const float t1 = tp1 + mb;

  #pragma unroll
  for (int ct = 0; ct < 8; ++ct) {
    float bi = b_in[ct * 16 + cb];
    u16* d0 = enh0 + (ct >> 1) * 640 + (ct & 1) * 16 + cb;
    u16* d1 = enh1 + (ct >> 1) * 640 + (ct & 1) * 16 + cb;
    #pragma unroll
    for (int i = 0; i < 4; ++i) {
      d0[(qr * 4 + i) * 40] = f2bf(acc0[ct][i] + bi);
      d1[(qr * 4 + i) * 40] = f2bf(acc1[ct][i] + bi);
    }
  }
  #pragma unroll
  for (int g = 0; g < 2; ++g) {
    float t_ = g ? t1 : t0;
    u16* eW = g ? enh1 : enh0;
    float phi = 7.f * t_;
    float ss, cc, sd, cd;
    sincosf(phi * (float)(qr * 8 + 1), &ss, &cc);
    sincosf(phi, &sd, &cd);
    u16* pc = eW + 4 * 640 + cb * 40 + qr * 8;
    u16* ps = eW + 5 * 640 + cb * 40 + qr * 8;
    #pragma unroll
    for (int m = 0; m < 8; ++m) {
      pc[m] = f2bf(cc);
      ps[m] = f2bf(ss);
      float nc = cc * cd - ss * sd;
      ss = ss * cd + cc * sd;
      cc = nc;
    }
  }

  const u16* gbase = WegF + ln * 8;
  f32x4 g0 = vz, g1 = vz;
  #pragma unroll
  for (int kt = 0; kt < 6; ++kt) {
    short8 A0 = *(const short8*)(enh0 + kt * 640 + cb * 40 + qr * 8);
    short8 A1 = *(const short8*)(enh1 + kt * 640 + cb * 40 + qr * 8);
    short8 Bg = *(const short8*)(gbase + (size_t)(kt * 17 + 16) * 512);
    g0 = __builtin_amdgcn_mfma_f32_16x16x32_bf16(A0, Bg, g0, 0, 0, 0);
    g1 = __builtin_amdgcn_mfma_f32_16x16x32_bf16(A1, Bg, g1, 0, 0, 0);
  }

  float ge0[4][4], ge1[4][4];
  {
    float bg = b_gate[cb & 3];
    #pragma unroll
    for (int i = 0; i < 4; ++i) {
      {
        float gi = g0[i] + bg;
        float mx = fmaxf(gi, __shfl_xor(gi, 1));
        mx = fmaxf(mx, __shfl_xor(mx, 2));
        float ev = __expf(gi - mx);
        float sv = ev + __shfl_xor(ev, 1);
        sv += __shfl_xor(sv, 2);
        float g = ev / sv;
        int base = qr * 16;
        ge0[0][i] = __shfl(g, base + 0);
        ge0[1][i] = __shfl(g, base + 1);
        ge0[2][i] = __shfl(g, base + 2);
        ge0[3][i] = __shfl(g, base + 3);
      }
      {
        float gi = g1[i] + bg;
        float mx = fmaxf(gi, __shfl_xor(gi, 1));
        mx = fmaxf(mx, __shfl_xor(mx, 2));
        float ev = __expf(gi - mx);
        float sv = ev + __shfl_xor(ev, 1);
        sv += __shfl_xor(sv, 2);
        float g = ev / sv;
        int base = qr * 16;
        ge1[0][i] = __shfl(g, base + 0);
        ge1[1][i] = __shfl(g, base + 1);
        ge1[2][i] = __shfl(g, base + 2);
        ge1[3][i] = __shfl(g, base + 3);
      }
    }
  }

  f32x4 ae0[16], ae1[16];
  #pragma unroll
  for (int c = 0; c < 16; ++c) { ae0[c] = vz; ae1[c] = vz; }
  for (int kt = 0; kt < 6; ++kt) {
    __syncthreads();
    {
      const u16* src = WegF + (size_t)kt * 17 * 512 + tid * 8;
      short8 s0 = *(const short8*)(src);
      short8 s1 = *(const short8*)(src + 2048);
      short8 s2 = *(const short8*)(src + 4096);
      short8 s3 = *(const short8*)(src + 6144);
      *(short8*)(stg + tid * 8) = s0;
      *(short8*)(stg + 2048 + tid * 8) = s1;
      *(short8*)(stg + 4096 + tid * 8) = s2;
      *(short8*)(stg + 6144 + tid * 8) = s3;
    }
    __syncthreads();
    short8 A0 = *(const short8*)(enh0 + kt * 640 + cb * 40 + qr * 8);
    short8 A1 = *(const short8*)(enh1 + kt * 640 + cb * 40 + qr * 8);
    #pragma unroll
    for (int c = 0; c < 16; ++c) {
      short8 Bf = *(const short8*)(stg + c * 512 + ln * 8);
      ae0[c] = __builtin_amdgcn_mfma_f32_16x16x32_bf16(A0, Bf, ae0[c], 0, 0, 0);
      ae1[c] = __builtin_amdgcn_mfma_f32_16x16x32_bf16(A1, Bf, ae1[c], 0, 0, 0);
    }
  }

  f32x4 cA[4], cB[4];
  #pragma unroll
  for (int i = 0; i < 4; ++i) { cA[i] = vz; cB[i] = vz; }
  #pragma unroll
  for (int e = 0; e < 4; ++e) {
    #pragma unroll
    for (int c2 = 0; c2 < 4; ++c2) {
      float be = b_exp[e * 64 + c2 * 16 + cb];
      #pragma unroll
      for (int i = 0; i < 4; ++i) {
        cA[c2][i] += ge0[e][i] * fmaxf(ae0[e * 4 + c2][i] + be, 0.f);
        cB[c2][i] += ge1[e][i] * fmaxf(ae1[e * 4 + c2][i] + be, 0.f);
      }
    }
  }
  #pragma unroll
  for (int c2 = 0; c2 < 4; ++c2) {
    u16* d0 = cmb0 + (c2 >> 1) * 640 + (c2 & 1) * 16 + cb;
    u16* d1 = cmb1 + (c2 >> 1) * 640 + (c2 & 1) * 16 + cb;
    #pragma unroll
    for (int i = 0; i < 4; ++i) {
      d0[(qr * 4 + i) * 40] = f2bf(cA[c2][i]);
      d1[(qr * 4 + i) * 40] = f2bf(cB[c2][i]);
    }
  }

  __syncthreads();
  {
    const u16* src = WctxF + tid * 8;
    short8 s0 = *(const short8*)(src);
    short8 s1 = *(const short8*)(src + 2048);
    short8 s2 = *(const short8*)(src + 4096);
    short8 s3 = *(const short8*)(src + 6144);
    *(short8*)(stg + tid * 8) = s0;
    *(short8*)(stg + 2048 + tid * 8) = s1;
    *(short8*)(stg + 4096 + tid * 8) = s2;
    *(short8*)(stg + 6144 + tid * 8) = s3;
  }
  __syncthreads();
  f32x4 c30[8], c31[8];
  #pragma unroll
  for (int i = 0; i < 8; ++i) { c30[i] = vz; c31[i] = vz; }
  #pragma unroll
  for (int kt = 0; kt < 2; ++kt) {
    short8 A0 = *(const short8*)(cmb0 + kt * 640 + cb * 40 + qr * 8);
    short8 A1 = *(const short8*)(cmb1 + kt * 640 + cb * 40 + qr * 8);
    #pragma unroll
    for (int ct = 0; ct < 8; ++ct) {
      short8 Bf = *(const short8*)(stg + (kt * 8 + ct) * 512 + ln * 8);
      c30[ct] = __builtin_amdgcn_mfma_f32_16x16x32_bf16(A0, Bf, c30[ct], 0, 0, 0);
      c31[ct] = __builtin_amdgcn_mfma_f32_16x16x32_bf16(A1, Bf, c31[ct], 0, 0, 0);
    }
  }
  #pragma unroll
  for (int ct = 0; ct < 8; ++ct) {
    float bc = b_ctx[ct * 16 + cb];
    u16* d0 = ctx0 + ct * 16 + cb;
    u16* d1 = ctx1 + ct * 16 + cb;
    #pragma unroll
    for (int i = 0; i < 4; ++i) {
      float v0 = c30[ct][i] + bc;
      float e0 = __expf(2.f * v0);
      d0[(qr * 4 + i) * 136] = f2bf(1.f - 2.f / (e0 + 1.f));
      float v1 = c31[ct][i] + bc;
      float e1 = __expf(2.f * v1);
      d1[(qr * 4 + i) * 136] = f2bf(1.f - 2.f / (e1 + 1.f));
    }
  }

  __syncthreads();
  {
    short8 s0 = *(const short8*)(WoutF + tid * 8);
    *(short8*)(stg + tid * 8) = s0;
  }
  __syncthreads();
  f32x4 a40 = vz, a41 = vz;
  #pragma unroll
  for (int kt = 0; kt < 4; ++kt) {
    short8 A0 = *(const short8*)(ctx0 + cb * 136 + kt * 32 + qr * 8);
    short8 A1 = *(const short8*)(ctx1 + cb * 136 + kt * 32 + qr * 8);
    short8 Bf = *(const short8*)(stg + kt * 512 + ln * 8);
    a40 = __builtin_amdgcn_mfma_f32_16x16x32_bf16(A0, Bf, a40, 0, 0, 0);
    a41 = __builtin_amdgcn_mfma_f32_16x16x32_bf16(A1, Bf, a41, 0, 0, 0);
  }
  if (cb < 3) {
    float bo = b_out[cb];
    #pragma unroll
    for (int i = 0; i < 4; ++i) {
      out[(size_t)(grow + qr * 4 + i) * 3 + cb] = a40[i] + bo;
      out[(size_t)(grow + 16 + qr * 4 + i) * 3 + cb] = a41[i] + bo;
    }
  }
}

extern "C" void kernel_launch(void* const* d_in, const int* in_sizes, int n_in,
                              void* d_out, int out_size, void* d_ws, size_t ws_size,
                              hipStream_t stream) {
  const float* x      = (const float*)d_in[0];
  const float* W_in   = (const float*)d_in[1];
  const float* b_in   = (const float*)d_in[2];
  const float* W_gate = (const float*)d_in[3];
  const float* b_gate = (const float*)d_in[4];
  const float* W_exp  = (const float*)d_in[5];
  const float* b_exp  = (const float*)d_in[6];
  const float* W_ctx  = (const float*)d_in[7];
  const float* b_ctx  = (const float*)d_in[8];
  const float* W_out  = (const float*)d_in[9];
  const float* b_out  = (const float*)d_in[10];
  float* out = (float*)d_out;

  char* ws = (char*)d_ws;
  float* wm  = (float*)(ws + OFF_WM);
  u16* WinF  = (u16*)(ws + OFF_WINF);
  u16* WegF  = (u16*)(ws + OFF_WEGF);
  u16* WctxF = (u16*)(ws + OFF_WCTXF);
  u16* WoutF = (u16*)(ws + OFF_WOUTF);
  float* t   = (float*)(ws + OFF_T);
  u16* xf    = (u16*)(ws + OFF_XF);

  const int B = in_sizes[0] / 784;
  const int nrt = B / 16;
  const size_t need = (size_t)OFF_XF + (size_t)nrt * 25 * 64 * 8 * sizeof(u16);

  prep_kernel<<<648, 256, 0, stream>>>(W_in, b_in, W_gate, W_exp, W_ctx, W_out,
                                       wm, WinF, WegF, WctxF, WoutF);
  if (ws_size >= need) {
    prepx_kernel<<<(nrt + 3) / 4, 256, 0, stream>>>(x, wm, xf, t, nrt);
    fused_kernel_xf<<<B / 128, 256, 0, stream>>>(xf, t, b_in, b_gate, b_exp, b_ctx,
                                                 b_out, wm, WinF, WegF, WctxF, WoutF,
                                                 out);
  } else {
    fused_kernel_x<<<B / 128, 256, 0, stream>>>(x, b_in, b_gate, b_exp, b_ctx, b_out,
                                                wm, WinF, WegF, WctxF, WoutF, out);
  }
}

// Round 9
// 327.128 us; speedup vs baseline: 1.1731x; 1.1731x over previous
//
#include <hip/hip_runtime.h>

typedef unsigned short u16;
typedef unsigned int u32;
typedef __attribute__((ext_vector_type(8))) short short8;   // 8 x bf16
typedef __attribute__((ext_vector_type(4))) float f32x4;

// ---------------- workspace layout (bytes) ----------------
#define OFF_WM    0         // float[801]: wmean[0..799] (pad 0), [800]=mean(b_in)
#define OFF_WINF  3584      // u16 [25][8][64][8]  W_in B-fragment-linear   (204800 B)
#define OFF_WEGF  208384    // u16 [6][17][64][8]  experts+gate frag-linear (104448 B)
#define OFF_WCTXF 312832    // u16 [2][8][64][8]   W_ctx frag-linear        (16384 B)
#define OFF_WOUTF 329216    // u16 [4][64][8]      W_out frag-linear        (4096 B)

__device__ __forceinline__ u16 f2bf(float x) {
  union { float f; u32 u; } v; v.f = x;
  u32 r = v.u + 0x7FFFu + ((v.u >> 16) & 1u);   // RNE
  return (u16)(r >> 16);
}

// ------------------------------------------------------------------
// Prep: wmean for the exact fp32 t path; all weights -> bf16 in
// MFMA-B-fragment-linear order: frag[tile][lane][j] with
// k = kt*32 + (lane>>4)*8 + j, n = ct*16 + (lane&15).
// ------------------------------------------------------------------
__global__ void prep_kernel(const float* __restrict__ W_in, const float* __restrict__ b_in,
                            const float* __restrict__ W_gate, const float* __restrict__ W_exp,
                            const float* __restrict__ W_ctx, const float* __restrict__ W_out,
                            float* __restrict__ wm, u16* __restrict__ WinF,
                            u16* __restrict__ WegF, u16* __restrict__ WctxF,
                            u16* __restrict__ WoutF) {
  int idx = blockIdx.x * 256 + threadIdx.x;
  if (idx < 801) {
    if (idx == 800) {
      float s = 0.f;
      for (int j = 0; j < 128; ++j) s += b_in[j];
      wm[800] = s * (1.f / 128.f);
    } else if (idx >= 784) {
      wm[idx] = 0.f;
    } else {
      float s = 0.f;
      for (int j = 0; j < 128; ++j) s += W_in[idx * 128 + j];
      wm[idx] = s * (1.f / 128.f);
    }
  } else if (idx < 103201) {                    // WinF: 25*8 tiles
    int f = idx - 801;
    int j = f & 7, lane = (f >> 3) & 63, tile = f >> 9;
    int ct = tile & 7, kt = tile >> 3;
    int k = kt * 32 + ((lane >> 4) << 3) + j;
    int n = ct * 16 + (lane & 15);
    WinF[f] = (k < 784) ? f2bf(W_in[k * 128 + n]) : (u16)0;
  } else if (idx < 155425) {                    // WegF: 6*17 tiles
    int f = idx - 103201;
    int j = f & 7, lane = (f >> 3) & 63, tile = f >> 9;
    int kt = tile / 17, ct = tile - kt * 17;
    int k = kt * 32 + ((lane >> 4) << 3) + j;
    int n = ct * 16 + (lane & 15);
    float v = 0.f;
    if (n < 256) { int e = n >> 6, h = n & 63; v = W_exp[(e * 192 + k) * 64 + h]; }
    else if (n < 260) v = W_gate[k * 4 + (n - 256)];
    WegF[f] = f2bf(v);
  } else if (idx < 163617) {                    // WctxF: 2*8 tiles
    int f = idx - 155425;
    int j = f & 7, lane = (f >> 3) & 63, tile = f >> 9;
    int ct = tile & 7, kt = tile >> 3;
    int k = kt * 32 + ((lane >> 4) << 3) + j;
    int n = ct * 16 + (lane & 15);
    WctxF[f] = f2bf(W_ctx[k * 128 + n]);
  } else if (idx < 165665) {                    // WoutF: 4 tiles (N padded 3->16)
    int f = idx - 163617;
    int j = f & 7, lane = (f >> 3) & 63, kt = f >> 9;
    int k = kt * 32 + ((lane >> 4) << 3) + j;
    int n = lane & 15;
    WoutF[f] = (n < 3) ? f2bf(W_out[k * 3 + n]) : (u16)0;
  }
}

// ------------------------------------------------------------------
// Fused forward: 4 waves/WG, each wave owns 32 rows (two 16-row MFMA
// groups, the round-4 sweet spot), weight fragments block-staged in
// LDS (round 6). This is the best verified configuration (329 us).
//
// Session conclusion (rounds 0-8): the fused window is bound by HBM
// contention with the harness's 822 MB workspace re-poison write-back
// draining during our kernels: (822 WB + 104 read) MB / ~7 TB/s ~=
// 130 us ~= every fused duration measured across all structural
// variants (barrier-free/staged, private/shared weights, 16/32/64
// rows per wave, pre-packed x). Kernel-side restructuring cannot beat
// that drain window; this variant captures residual read BW best.
//
// LDS (77824 B/block -> 2 blocks/CU):
//   per-wave enh: 2 groups x 3840 u16 (7680 u16/wave, 4 waves)
//     enh [6][16][40]; cmb aliases [0,1280); ctx aliases [1280,3456)
//     (same-wave DS ordering makes aliasing safe)
//   stage: 8192 u16 shared. Phase 1: 2 x 4096 (double-buffered kt).
//     Phase 2: 16 expert tiles/kt. Phase 3: 16 W_ctx tiles.
//     Phase 4: 4 W_out tiles.
// Barriers: uniform control flow only (lane-divergent k0<784 branch
// contains no barrier).
// ------------------------------------------------------------------
__global__ __launch_bounds__(256, 2)
void fused_kernel(const float* __restrict__ x,
                  const float* __restrict__ b_in, const float* __restrict__ b_gate,
                  const float* __restrict__ b_exp, const float* __restrict__ b_ctx,
                  const float* __restrict__ b_out,
                  const float* __restrict__ wm, const u16* __restrict__ WinF,
                  const u16* __restrict__ WegF, const u16* __restrict__ WctxF,
                  const u16* __restrict__ WoutF,
                  float* __restrict__ out) {
  __shared__ __align__(16) u16 smem[4 * 7680 + 8192];
  const int tid = threadIdx.x;
  const int wv = tid >> 6;
  const int ln = tid & 63;
  const int cb = ln & 15;        // fragment col / A-row
  const int qr = ln >> 4;        // k-quad
  u16* enh0 = smem + wv * 7680;
  u16* enh1 = enh0 + 3840;
  u16* cmb0 = enh0;
  u16* cmb1 = enh1;
  u16* ctx0 = enh0 + 1280;
  u16* ctx1 = enh1 + 1280;
  u16* stg  = smem + 4 * 7680;   // 8192 u16 staging region

  const int grow = blockIdx.x * 128 + wv * 32;    // this wave's first row
  const float* xr0 = x + (size_t)(grow + cb) * 784;
  const float* xr1 = xr0 + (size_t)16 * 784;

  const f32x4 vz = {0.f, 0.f, 0.f, 0.f};

  // ---- Phase 1: projected = x @ W_in (MFMA) + exact fp32 t, 2 row-groups ----
  f32x4 acc0[8], acc1[8];
  #pragma unroll
  for (int i = 0; i < 8; ++i) { acc0[i] = vz; acc1[i] = vz; }
  float tp0 = 0.f, tp1 = 0.f;

  // prologue: stage kt=0 weight tiles into buffer 0
  {
    const u16* src = WinF + tid * 8;
    short8 r0 = *(const short8*)(src);
    short8 r1 = *(const short8*)(src + 2048);
    *(short8*)(stg + tid * 8) = r0;
    *(short8*)(stg + 2048 + tid * 8) = r1;
  }
  __syncthreads();

  for (int kt = 0; kt < 25; ++kt) {
    const int buf = (kt & 1) << 12;               // 0 or 4096 u16
    // prefetch next kt's tiles to registers (write to LDS after compute)
    short8 r0 = short8{0,0,0,0,0,0,0,0}, r1 = r0;
    const bool pf = (kt < 24);
    if (pf) {
      const u16* src = WinF + (size_t)(kt + 1) * 4096 + tid * 8;
      r0 = *(const short8*)(src);
      r1 = *(const short8*)(src + 2048);
    }

    const int k0 = kt * 32 + qr * 8;
    union { short8 s; u32 u[4]; } af, bf;
    {
      float4 a0 = make_float4(0.f, 0.f, 0.f, 0.f), a1 = a0;
      float4 b0 = a0, b1 = a0, m0 = a0, m1 = a0;
      if (k0 < 784) {                     // K-tail: zero A (staged pad also 0)
        a0 = *(const float4*)(xr0 + k0);
        a1 = *(const float4*)(xr0 + k0 + 4);
        b0 = *(const float4*)(xr1 + k0);
        b1 = *(const float4*)(xr1 + k0 + 4);
        m0 = *(const float4*)(wm + k0);
        m1 = *(const float4*)(wm + k0 + 4);
        tp0 += a0.x * m0.x + a0.y * m0.y + a0.z * m0.z + a0.w * m0.w
             + a1.x * m1.x + a1.y * m1.y + a1.z * m1.z + a1.w * m1.w;
        tp1 += b0.x * m0.x + b0.y * m0.y + b0.z * m0.z + b0.w * m0.w
             + b1.x * m1.x + b1.y * m1.y + b1.z * m1.z + b1.w * m1.w;
      }
      af.u[0] = (u32)f2bf(a0.x) | ((u32)f2bf(a0.y) << 16);
      af.u[1] = (u32)f2bf(a0.z) | ((u32)f2bf(a0.w) << 16);
      af.u[2] = (u32)f2bf(a1.x) | ((u32)f2bf(a1.y) << 16);
      af.u[3] = (u32)f2bf(a1.z) | ((u32)f2bf(a1.w) << 16);
      bf.u[0] = (u32)f2bf(b0.x) | ((u32)f2bf(b0.y) << 16);
      bf.u[1] = (u32)f2bf(b0.z) | ((u32)f2bf(b0.w) << 16);
      bf.u[2] = (u32)f2bf(b1.x) | ((u32)f2bf(b1.y) << 16);
      bf.u[3] = (u32)f2bf(b1.z) | ((u32)f2bf(b1.w) << 16);
    }

    // weight fragments from LDS (staged): ds_read_b128, 2-way alias = free
    short8 Bf[8];
    #pragma unroll
    for (int ct = 0; ct < 8; ++ct)
      Bf[ct] = *(const short8*)(stg + buf + ct * 512 + ln * 8);

    #pragma unroll
    for (int ct = 0; ct < 8; ++ct) {
      acc0[ct] = __builtin_amdgcn_mfma_f32_16x16x32_bf16(af.s, Bf[ct], acc0[ct], 0, 0, 0);
      acc1[ct] = __builtin_amdgcn_mfma_f32_16x16x32_bf16(bf.s, Bf[ct], acc1[ct], 0, 0, 0);
    }

    if (pf) {
      u16* dst = stg + (buf ^ 4096);
      *(short8*)(dst + tid * 8) = r0;
      *(short8*)(dst + 2048 + tid * 8) = r1;
    }
    __syncthreads();    // next-kt staging visible; prior buffer free to overwrite
  }

  // t: reduce partials across the 4 k-quads of row cb
  tp0 += __shfl_xor(tp0, 16);
  tp0 += __shfl_xor(tp0, 32);
  tp1 += __shfl_xor(tp1, 16);
  tp1 += __shfl_xor(tp1, 32);
  const float mb = wm[800];
  const float t0 = tp0 + mb;
  const float t1 = tp1 + mb;

  // enhanced[cols 0..127] = projected + b_in  (bf16, chunked [6][16][40])
  #pragma unroll
  for (int ct = 0; ct < 8; ++ct) {
    float bi = b_in[ct * 16 + cb];
    u16* d0 = enh0 + (ct >> 1) * 640 + (ct & 1) * 16 + cb;
    u16* d1 = enh1 + (ct >> 1) * 640 + (ct & 1) * 16 + cb;
    #pragma unroll
    for (int i = 0; i < 4; ++i) {
      d0[(qr * 4 + i) * 40] = f2bf(acc0[ct][i] + bi);
      d1[(qr * 4 + i) * 40] = f2bf(acc1[ct][i] + bi);
    }
  }
  // enhanced[cols 128..191] = phasor bank, per group.
  #pragma unroll
  for (int g = 0; g < 2; ++g) {
    float t = g ? t1 : t0;
    u16* eW = g ? enh1 : enh0;
    float phi = 7.f * t;
    float ss, cc, sd, cd;
    sincosf(phi * (float)(qr * 8 + 1), &ss, &cc);
    sincosf(phi, &sd, &cd);
    u16* pc = eW + 4 * 640 + cb * 40 + qr * 8;
    u16* ps = eW + 5 * 640 + cb * 40 + qr * 8;
    #pragma unroll
    for (int m = 0; m < 8; ++m) {
      pc[m] = f2bf(cc);
      ps[m] = f2bf(ss);
      float nc = cc * cd - ss * sd;
      ss = ss * cd + cc * sd;
      cc = nc;
    }
  }

  // ---- Phase 2: gate (private loads) then experts (staged per kt) ----
  const u16* gbase = WegF + ln * 8;
  f32x4 g0 = vz, g1 = vz;
  #pragma unroll
  for (int kt = 0; kt < 6; ++kt) {
    short8 A0 = *(const short8*)(enh0 + kt * 640 + cb * 40 + qr * 8);
    short8 A1 = *(const short8*)(enh1 + kt * 640 + cb * 40 + qr * 8);
    short8 Bg = *(const short8*)(gbase + (size_t)(kt * 17 + 16) * 512);
    g0 = __builtin_amdgcn_mfma_f32_16x16x32_bf16(A0, Bg, g0, 0, 0, 0);
    g1 = __builtin_amdgcn_mfma_f32_16x16x32_bf16(A1, Bg, g1, 0, 0, 0);
  }

  // softmax over expert lanes cb=0..3 of each quad, broadcast to all lanes
  float ge0[4][4], ge1[4][4];              // [expert][i]
  {
    float bg = b_gate[cb & 3];
    #pragma unroll
    for (int i = 0; i < 4; ++i) {
      {
        float gi = g0[i] + bg;
        float mx = fmaxf(gi, __shfl_xor(gi, 1));
        mx = fmaxf(mx, __shfl_xor(mx, 2));
        float ev = __expf(gi - mx);
        float sv = ev + __shfl_xor(ev, 1);
        sv += __shfl_xor(sv, 2);
        float g = ev / sv;
        int base = qr * 16;
        ge0[0][i] = __shfl(g, base + 0);
        ge0[1][i] = __shfl(g, base + 1);
        ge0[2][i] = __shfl(g, base + 2);
        ge0[3][i] = __shfl(g, base + 3);
      }
      {
        float gi = g1[i] + bg;
        float mx = fmaxf(gi, __shfl_xor(gi, 1));
        mx = fmaxf(mx, __shfl_xor(mx, 2));
        float ev = __expf(gi - mx);
        float sv = ev + __shfl_xor(ev, 1);
        sv += __shfl_xor(sv, 2);
        float g = ev / sv;
        int base = qr * 16;
        ge1[0][i] = __shfl(g, base + 0);
        ge1[1][i] = __shfl(g, base + 1);
        ge1[2][i] = __shfl(g, base + 2);
        ge1[3][i] = __shfl(g, base + 3);
      }
    }
  }

  // experts: kt-outer, 16 expert tiles staged per kt, shared by all waves
  f32x4 ae0[16], ae1[16];
  #pragma unroll
  for (int c = 0; c < 16; ++c) { ae0[c] = vz; ae1[c] = vz; }
  for (int kt = 0; kt < 6; ++kt) {
    __syncthreads();                    // prior stg readers done
    {
      const u16* src = WegF + (size_t)kt * 17 * 512 + tid * 8;
      short8 s0 = *(const short8*)(src);
      short8 s1 = *(const short8*)(src + 2048);
      short8 s2 = *(const short8*)(src + 4096);
      short8 s3 = *(const short8*)(src + 6144);
      *(short8*)(stg + tid * 8) = s0;
      *(short8*)(stg + 2048 + tid * 8) = s1;
      *(short8*)(stg + 4096 + tid * 8) = s2;
      *(short8*)(stg + 6144 + tid * 8) = s3;
    }
    __syncthreads();
    short8 A0 = *(const short8*)(enh0 + kt * 640 + cb * 40 + qr * 8);
    short8 A1 = *(const short8*)(enh1 + kt * 640 + cb * 40 + qr * 8);
    #pragma unroll
    for (int c = 0; c < 16; ++c) {
      short8 Bf = *(const short8*)(stg + c * 512 + ln * 8);
      ae0[c] = __builtin_amdgcn_mfma_f32_16x16x32_bf16(A0, Bf, ae0[c], 0, 0, 0);
      ae1[c] = __builtin_amdgcn_mfma_f32_16x16x32_bf16(A1, Bf, ae1[c], 0, 0, 0);
    }
  }

  // combined = sum_e gate_e * relu(expert_e)
  f32x4 cA[4], cB[4];
  #pragma unroll
  for (int i = 0; i < 4; ++i) { cA[i] = vz; cB[i] = vz; }
  #pragma unroll
  for (int e = 0; e < 4; ++e) {
    #pragma unroll
    for (int c2 = 0; c2 < 4; ++c2) {
      float be = b_exp[e * 64 + c2 * 16 + cb];
      #pragma unroll
      for (int i = 0; i < 4; ++i) {
        cA[c2][i] += ge0[e][i] * fmaxf(ae0[e * 4 + c2][i] + be, 0.f);
        cB[c2][i] += ge1[e][i] * fmaxf(ae1[e * 4 + c2][i] + be, 0.f);
      }
    }
  }
  // combined -> LDS (bf16, [2][16][40]); same-wave enh reads all precede
  #pragma unroll
  for (int c2 = 0; c2 < 4; ++c2) {
    u16* d0 = cmb0 + (c2 >> 1) * 640 + (c2 & 1) * 16 + cb;
    u16* d1 = cmb1 + (c2 >> 1) * 640 + (c2 & 1) * 16 + cb;
    #pragma unroll
    for (int i = 0; i < 4; ++i) {
      d0[(qr * 4 + i) * 40] = f2bf(cA[c2][i]);
      d1[(qr * 4 + i) * 40] = f2bf(cB[c2][i]);
    }
  }

  // ---- Phase 3: ctx = tanh(combined @ W_ctx + b_ctx), K=64, staged ----
  __syncthreads();                      // phase-2 stg readers done
  {
    const u16* src = WctxF + tid * 8;
    short8 s0 = *(const short8*)(src);
    short8 s1 = *(const short8*)(src + 2048);
    short8 s2 = *(const short8*)(src + 4096);
    short8 s3 = *(const short8*)(src + 6144);
    *(short8*)(stg + tid * 8) = s0;
    *(short8*)(stg + 2048 + tid * 8) = s1;
    *(short8*)(stg + 4096 + tid * 8) = s2;
    *(short8*)(stg + 6144 + tid * 8) = s3;
  }
  __syncthreads();
  f32x4 c30[8], c31[8];
  #pragma unroll
  for (int i = 0; i < 8; ++i) { c30[i] = vz; c31[i] = vz; }
  #pragma unroll
  for (int kt = 0; kt < 2; ++kt) {
    short8 A0 = *(const short8*)(cmb0 + kt * 640 + cb * 40 + qr * 8);
    short8 A1 = *(const short8*)(cmb1 + kt * 640 + cb * 40 + qr * 8);
    #pragma unroll
    for (int ct = 0; ct < 8; ++ct) {
      short8 Bf = *(const short8*)(stg + (kt * 8 + ct) * 512 + ln * 8);
      c30[ct] = __builtin_amdgcn_mfma_f32_16x16x32_bf16(A0, Bf, c30[ct], 0, 0, 0);
      c31[ct] = __builtin_amdgcn_mfma_f32_16x16x32_bf16(A1, Bf, c31[ct], 0, 0, 0);
    }
  }
  #pragma unroll
  for (int ct = 0; ct < 8; ++ct) {
    float bc = b_ctx[ct * 16 + cb];
    u16* d0 = ctx0 + ct * 16 + cb;
    u16* d1 = ctx1 + ct * 16 + cb;
    #pragma unroll
    for (int i = 0; i < 4; ++i) {
      float v0 = c30[ct][i] + bc;
      float e0 = __expf(2.f * v0);           // tanh via exp; saturates correctly
      d0[(qr * 4 + i) * 136] = f2bf(1.f - 2.f / (e0 + 1.f));
      float v1 = c31[ct][i] + bc;
      float e1 = __expf(2.f * v1);
      d1[(qr * 4 + i) * 136] = f2bf(1.f - 2.f / (e1 + 1.f));
    }
  }

  // ---- Phase 4: logits = ctx @ W_out + b_out (MFMA, N padded to 16) ----
  __syncthreads();                      // phase-3 stg readers done
  {
    short8 s0 = *(const short8*)(WoutF + tid * 8);   // 2048 u16 total
    *(short8*)(stg + tid * 8) = s0;
  }
  __syncthreads();
  f32x4 a40 = vz, a41 = vz;
  #pragma unroll
  for (int kt = 0; kt < 4; ++kt) {
    short8 A0 = *(const short8*)(ctx0 + cb * 136 + kt * 32 + qr * 8);
    short8 A1 = *(const short8*)(ctx1 + cb * 136 + kt * 32 + qr * 8);
    short8 Bf = *(const short8*)(stg + kt * 512 + ln * 8);
    a40 = __builtin_amdgcn_mfma_f32_16x16x32_bf16(A0, Bf, a40, 0, 0, 0);
    a41 = __builtin_amdgcn_mfma_f32_16x16x32_bf16(A1, Bf, a41, 0, 0, 0);
  }
  if (cb < 3) {
    float bo = b_out[cb];
    #pragma unroll
    for (int i = 0; i < 4; ++i) {
      out[(size_t)(grow + qr * 4 + i) * 3 + cb] = a40[i] + bo;
      out[(size_t)(grow + 16 + qr * 4 + i) * 3 + cb] = a41[i] + bo;
    }
  }
}

extern "C" void kernel_launch(void* const* d_in, const int* in_sizes, int n_in,
                              void* d_out, int out_size, void* d_ws, size_t ws_size,
                              hipStream_t stream) {
  const float* x      = (const float*)d_in[0];
  const float* W_in   = (const float*)d_in[1];
  const float* b_in   = (const float*)d_in[2];
  const float* W_gate = (const float*)d_in[3];
  const float* b_gate = (const float*)d_in[4];
  const float* W_exp  = (const float*)d_in[5];
  const float* b_exp  = (const float*)d_in[6];
  const float* W_ctx  = (const float*)d_in[7];
  const float* b_ctx  = (const float*)d_in[8];
  const float* W_out  = (const float*)d_in[9];
  const float* b_out  = (const float*)d_in[10];
  float* out = (float*)d_out;

  char* ws = (char*)d_ws;
  float* wm  = (float*)(ws + OFF_WM);
  u16* WinF  = (u16*)(ws + OFF_WINF);
  u16* WegF  = (u16*)(ws + OFF_WEGF);
  u16* WctxF = (u16*)(ws + OFF_WCTXF);
  u16* WoutF = (u16*)(ws + OFF_WOUTF);

  const int B = in_sizes[0] / 784;
  prep_kernel<<<648, 256, 0, stream>>>(W_in, b_in, W_gate, W_exp, W_ctx, W_out,
                                       wm, WinF, WegF, WctxF, WoutF);
  fused_kernel<<<B / 128, 256, 0, stream>>>(x, b_in, b_gate, b_exp, b_ctx, b_out,
                                            wm, WinF, WegF, WctxF, WoutF, out);
}